// Round 2
// baseline (521.661 us; speedup 1.0000x reference)
//
#include <hip/hip_runtime.h>

// MS-SSIM, 5 levels, 16x3x512x512 fp32, scalar fp32 out.
//
// R7: 3-launch structure (was 7). No cooperative launch, no grid sync,
// no atomics, no memset.
//  - l0_kernel: R5's T=64 tile (h/v s-d conv) for level 0 + MULTIPOOL:
//    each block's 64x32 core pools hierarchically to X1(2x2),X2(4x4),
//    X3(8x8),X4(16x16) -- in-thread recompute with the exact repeated-2x2
//    expression, bitwise == level-by-level pooling. L0's grid tiles the
//    512x512 image exactly, so all four pyramid buffers are complete
//    after one kernel.
//  - tail_kernel: levels 1..4 SSIM are then independent -> ONE launch,
//    2784 blocks (1536 L1-T64 + 768 L2-T32 + 384 L3-T16 + 96 L4-T16),
//    per-block template dispatch (block-uniform branch).
//  - finalize_kernel: sums per-block partial slots (written
//    unconditionally -> workspace re-poison safe), applies pow weights.

#define NTHR 512

typedef float v4  __attribute__((ext_vector_type(4)));
typedef float v2f __attribute__((ext_vector_type(2)));

__device__ __forceinline__ float frcp(float x) { return __builtin_amdgcn_rcpf(x); }

// 2^L x 2^L hierarchical mean == L repeated 2x2 avg-pools, bitwise.
template<int L>
__device__ __forceinline__ float poolv(const float* __restrict__ p, int H, int iy, int ix)
{
    if constexpr (L == 1) {
        const float* r0 = p + (size_t)iy * H + ix;
        const float* r1 = r0 + H;
        return 0.25f * ((r0[0] + r0[1]) + (r1[0] + r1[1]));
    } else {
        constexpr int s = 1 << (L - 1);
        return 0.25f * ((poolv<L-1>(p, H, iy, ix)     + poolv<L-1>(p, H, iy, ix + s))
                      + (poolv<L-1>(p, H, iy + s, ix) + poolv<L-1>(p, H, iy + s, ix + s)));
    }
}

// One SSIM conv tile: h-pass (s/d channel reduction) -> LDS -> v-pass ->
// block reduction -> private partial slot. Identical math to R5.
template<int TROWS>
__device__ void ssim_tile(const float* __restrict__ p1, const float* __restrict__ p2,
                          int H, int tx0, int ty0,
                          v4* hb, float* red,
                          float* __restrict__ partS, float* __restrict__ partC)
{
    constexpr int HR    = TROWS + 10;          // h-rows per tile
    constexpr int OPT   = TROWS * 32 / NTHR;   // output rows per thread
    constexpr int PITCH = 33;                  // v4 units per LDS row
    constexpr int NW    = NTHR / 64;           // waves per block

    const float GW[11] = {0.00102840f, 0.00759877f, 0.03600070f, 0.10936069f,
                          0.21300636f, 0.26601172f, 0.21300636f, 0.10936069f,
                          0.03600070f, 0.00759877f, 0.00102840f};
    const float C1 = 1e-4f, C2 = 9e-4f;

    const int tid   = threadIdx.x;
    const int outHW = H - 10;

    // ---- horizontal pass: HR rows x 8 col-groups (4 cols each)
    for (int task = tid; task < HR * 8; task += NTHR) {
        const int r  = task >> 3, cg2 = task & 7;
        const int gr = ty0 + r;
        const int c0 = tx0 + cg2 * 4;
        v4 hs = 0.f, hd = 0.f, hss = 0.f, hdd = 0.f;
        if (gr < H) {
            float s[16], d[16];
            if (c0 + 16 <= H) {
                const float* pa = p1 + (size_t)gr * H + c0;
                const float* pb = p2 + (size_t)gr * H + c0;
                #pragma unroll
                for (int q = 0; q < 4; ++q) {
                    v4 va = *(const v4*)(pa + 4 * q);
                    v4 vb = *(const v4*)(pb + 4 * q);
                    v4 sv = va + vb, dv = va - vb;
                    s[4*q+0] = sv.x; s[4*q+1] = sv.y; s[4*q+2] = sv.z; s[4*q+3] = sv.w;
                    d[4*q+0] = dv.x; d[4*q+1] = dv.y; d[4*q+2] = dv.z; d[4*q+3] = dv.w;
                }
            } else {
                #pragma unroll
                for (int q = 0; q < 16; ++q) {
                    int cc = c0 + q;
                    float a = (cc < H) ? p1[(size_t)gr * H + cc] : 0.f;
                    float b = (cc < H) ? p2[(size_t)gr * H + cc] : 0.f;
                    s[q] = a + b; d[q] = a - b;
                }
            }
            #pragma unroll
            for (int j = 0; j < 11; ++j) {
                float w = GW[j];
                v4 sv = {s[j], s[j+1], s[j+2], s[j+3]};
                v4 dv = {d[j], d[j+1], d[j+2], d[j+3]};
                v4 wsv = w * sv, wdv = w * dv;
                hs += wsv; hd += wdv; hss += wsv * sv; hdd += wdv * dv;
            }
        }
        v4* row = &hb[r * PITCH + cg2 * 4];
        row[0] = (v4){hs.x, hd.x, hss.x, hdd.x};
        row[1] = (v4){hs.y, hd.y, hss.y, hdd.y};
        row[2] = (v4){hs.z, hd.z, hss.z, hdd.z};
        row[3] = (v4){hs.w, hd.w, hss.w, hdd.w};
    }
    __syncthreads();

    // ---- vertical pass + ssim/cs: thread = 1 column x OPT rows
    const int col  = tid & 31;
    const int row0 = (tid >> 5) * OPT;
    const float colm = (tx0 + col < outHW) ? 1.f : 0.f;
    v4 A[OPT];
    #pragma unroll
    for (int k = 0; k < OPT; ++k) A[k] = 0.f;

    #pragma unroll
    for (int r = 0; r < OPT + 10; ++r) {
        v4 h = hb[(row0 + r) * PITCH + col];
        #pragma unroll
        for (int k = 0; k < OPT; ++k) {
            const int j = r - k;
            if (j >= 0 && j < 11) A[k] += GW[j] * h;
        }
    }

    float ssim_t = 0.f, cs_t = 0.f;
    #pragma unroll
    for (int k = 0; k < OPT; ++k) {
        float mask = colm * ((ty0 + row0 + k < outHW) ? 1.f : 0.f);
        float mu_s = A[k].x, mu_d = A[k].y;
        float P = mu_s * mu_s, Q = mu_d * mu_d;
        float U = A[k].z - P, V = A[k].w - Q;
        float v1 = 0.5f * (U - V) + C2;
        float v2 = 0.5f * (U + V) + C2;
        float n1 = 0.5f * (P - Q) + C1;
        float d1 = 0.5f * (P + Q) + C1;
        float csv = v1 * frcp(v2);
        float ssv = n1 * csv * frcp(d1);
        cs_t   += mask * csv;
        ssim_t += mask * ssv;
    }

    // ---- block reduction -> private partial slot (no atomics)
    #pragma unroll
    for (int off = 32; off > 0; off >>= 1) {
        ssim_t += __shfl_down(ssim_t, off);
        cs_t   += __shfl_down(cs_t, off);
    }
    int wave = tid >> 6, lane = tid & 63;
    if (lane == 0) { red[wave] = ssim_t; red[NW + wave] = cs_t; }
    __syncthreads();
    if (tid == 0) {
        float s = 0.f, c = 0.f;
        #pragma unroll
        for (int w = 0; w < NW; ++w) { s += red[w]; c += red[NW + w]; }
        partS[0] = s; partC[0] = c;
    }
}

// ---- level 0: SSIM tile + multipool (X1..X4 complete after this kernel)
__global__ __launch_bounds__(NTHR, 8) void l0_kernel(
    const float* __restrict__ img1, const float* __restrict__ img2,
    float* __restrict__ x1a, float* __restrict__ x1b,
    float* __restrict__ x2a, float* __restrict__ x2b,
    float* __restrict__ x3a, float* __restrict__ x3b,
    float* __restrict__ x4a, float* __restrict__ x4b,
    float* __restrict__ accS, float* __restrict__ accC)
{
    __shared__ v4 hb[74 * 33];
    __shared__ float red[16];

    const int tid = threadIdx.x;
    const int nc  = blockIdx.z;
    const int tx0 = blockIdx.x * 32;
    const int ty0 = blockIdx.y * 64;
    const int H   = 512;
    const float* p1 = img1 + (size_t)nc * H * H;
    const float* p2 = img2 + (size_t)nc * H * H;

    // multipool over this block's 64x32 core (tiles the image exactly):
    // tasks: 512 X1 + 128 X2 + 32 X3 + 8 X4 = 680
    for (int t = tid; t < 680; t += NTHR) {
        if (t < 512) {
            int r = t >> 4, c = t & 15;
            int iy = ty0 + 2 * r, ix = tx0 + 2 * c;
            size_t o = (size_t)nc * 256 * 256 + (size_t)((ty0 >> 1) + r) * 256 + ((tx0 >> 1) + c);
            x1a[o] = poolv<1>(p1, H, iy, ix);
            x1b[o] = poolv<1>(p2, H, iy, ix);
        } else if (t < 640) {
            int t2 = t - 512; int r = t2 >> 3, c = t2 & 7;
            int iy = ty0 + 4 * r, ix = tx0 + 4 * c;
            size_t o = (size_t)nc * 128 * 128 + (size_t)((ty0 >> 2) + r) * 128 + ((tx0 >> 2) + c);
            x2a[o] = poolv<2>(p1, H, iy, ix);
            x2b[o] = poolv<2>(p2, H, iy, ix);
        } else if (t < 672) {
            int t3 = t - 640; int r = t3 >> 2, c = t3 & 3;
            int iy = ty0 + 8 * r, ix = tx0 + 8 * c;
            size_t o = (size_t)nc * 64 * 64 + (size_t)((ty0 >> 3) + r) * 64 + ((tx0 >> 3) + c);
            x3a[o] = poolv<3>(p1, H, iy, ix);
            x3b[o] = poolv<3>(p2, H, iy, ix);
        } else {
            int t4 = t - 672; int r = t4 >> 1, c = t4 & 1;
            int iy = ty0 + 16 * r, ix = tx0 + 16 * c;
            size_t o = (size_t)nc * 32 * 32 + (size_t)((ty0 >> 4) + r) * 32 + ((tx0 >> 4) + c);
            x4a[o] = poolv<4>(p1, H, iy, ix);
            x4b[o] = poolv<4>(p2, H, iy, ix);
        }
    }

    int fb = (int)blockIdx.x + (int)gridDim.x * ((int)blockIdx.y + (int)gridDim.y * (int)blockIdx.z);
    ssim_tile<64>(p1, p2, H, tx0, ty0, hb, red, accS + fb, accC + fb);
}

// ---- levels 1..4 in one launch; block-uniform template dispatch
//   [0,1536):   L1  H=256 T=64  ct=8 rt=4
//   [1536,2304):L2  H=128 T=32  ct=4 rt=4
//   [2304,2688):L3  H=64  T=16  ct=2 rt=4
//   [2688,2784):L4  H=32  T=16  ct=1 rt=2
__global__ __launch_bounds__(NTHR, 8) void tail_kernel(
    const float* __restrict__ x1a, const float* __restrict__ x1b,
    const float* __restrict__ x2a, const float* __restrict__ x2b,
    const float* __restrict__ x3a, const float* __restrict__ x3b,
    const float* __restrict__ x4a, const float* __restrict__ x4b,
    float* __restrict__ accTS, float* __restrict__ accTC)
{
    __shared__ v4 hb[74 * 33];
    __shared__ float red[16];

    const int b = (int)blockIdx.x;
    if (b < 1536) {
        const int H = 256, ct = 8, rt = 4;
        int cx = b % ct, rem = b / ct, cy = rem % rt, nc = rem / rt;
        const float* p1 = x1a + (size_t)nc * H * H;
        const float* p2 = x1b + (size_t)nc * H * H;
        ssim_tile<64>(p1, p2, H, cx * 32, cy * 64, hb, red, accTS + b, accTC + b);
    } else if (b < 2304) {
        const int H = 128, ct = 4, rt = 4;
        int lb = b - 1536;
        int cx = lb % ct, rem = lb / ct, cy = rem % rt, nc = rem / rt;
        const float* p1 = x2a + (size_t)nc * H * H;
        const float* p2 = x2b + (size_t)nc * H * H;
        ssim_tile<32>(p1, p2, H, cx * 32, cy * 32, hb, red, accTS + b, accTC + b);
    } else if (b < 2688) {
        const int H = 64, ct = 2, rt = 4;
        int lb = b - 2304;
        int cx = lb % ct, rem = lb / ct, cy = rem % rt, nc = rem / rt;
        const float* p1 = x3a + (size_t)nc * H * H;
        const float* p2 = x3b + (size_t)nc * H * H;
        ssim_tile<16>(p1, p2, H, cx * 32, cy * 16, hb, red, accTS + b, accTC + b);
    } else {
        const int H = 32, ct = 1, rt = 2;
        int lb = b - 2688;
        int cx = lb % ct, rem = lb / ct, cy = rem % rt, nc = rem / rt;
        const float* p1 = x4a + (size_t)nc * H * H;
        const float* p2 = x4b + (size_t)nc * H * H;
        ssim_tile<16>(p1, p2, H, cx * 32, cy * 16, hb, red, accTS + b, accTC + b);
    }
}

// ---- finalize: sum partial slots, pow weights
__global__ void finalize_kernel(const float* __restrict__ acc0S, const float* __restrict__ acc0C,
                                const float* __restrict__ accTS, const float* __restrict__ accTC,
                                float* __restrict__ out)
{
    __shared__ float sm[10];
    __shared__ float wred[8];
    const int tid  = (int)threadIdx.x;
    const int wave = tid >> 6, lane = tid & 63;
    const int st[5] = {0, 0, 1536, 2304, 2688};
    const int en[5] = {6144, 1536, 2304, 2688, 2784};

    for (int srs = 0; srs < 10; ++srs) {
        int l = srs >> 1;
        const float* base = (srs & 1) ? (l == 0 ? acc0C : accTC)
                                      : (l == 0 ? acc0S : accTS);
        float p = 0.f;
        for (int i = st[l] + tid; i < en[l]; i += NTHR) p += base[i];
        #pragma unroll
        for (int o = 32; o > 0; o >>= 1) p += __shfl_down(p, o);
        if (lane == 0) wred[wave] = p;
        __syncthreads();
        if (tid == 0) {
            float t = 0.f;
            #pragma unroll
            for (int w = 0; w < 8; ++w) t += wred[w];
            sm[srs] = t;
        }
        __syncthreads();
    }

    if (tid == 0) {
        const float w[5] = {0.0448f, 0.2856f, 0.3001f, 0.2363f, 0.1333f};
        float ms[5], mc[5];
        for (int l = 0; l < 5; ++l) {
            int oh = (512 >> l) - 10;
            float cnt = 48.f * (float)oh * (float)oh;
            ms[l] = (sm[2 * l] / cnt + 1.f) * 0.5f;
            mc[l] = (sm[2 * l + 1] / cnt + 1.f) * 0.5f;
        }
        float p2 = powf(ms[4], w[4]);
        float r = 1.f;
        for (int i = 0; i < 4; ++i) r *= powf(mc[i], w[i]) * p2;
        out[0] = r;
    }
}

extern "C" void kernel_launch(void* const* d_in, const int* in_sizes, int n_in,
                              void* d_out, int out_size, void* d_ws, size_t ws_size,
                              hipStream_t stream)
{
    (void)in_sizes; (void)n_in; (void)out_size; (void)ws_size;
    const float* img1 = (const float*)d_in[0];
    const float* img2 = (const float*)d_in[1];
    float* out = (float*)d_out;
    float* ws  = (float*)d_ws;

    // workspace layout (floats):
    //   acc0S[6144] acc0C[6144] accTS[2784] accTC[2784]  (per-block partials)
    //   X1a X1b X2a X2b X3a X3b X4a X4b                  (pyramid buffers)
    float* acc0S = ws;
    float* acc0C = acc0S + 6144;
    float* accTS = acc0C + 6144;
    float* accTC = accTS + 2784;
    float* bufs  = accTC + 2784;              // offset 17856 floats (16B aligned)
    float* x1a = bufs;
    float* x1b = x1a + (size_t)48 * 256 * 256;
    float* x2a = x1b + (size_t)48 * 256 * 256;
    float* x2b = x2a + (size_t)48 * 128 * 128;
    float* x3a = x2b + (size_t)48 * 128 * 128;
    float* x3b = x3a + (size_t)48 * 64 * 64;
    float* x4a = x3b + (size_t)48 * 64 * 64;
    float* x4b = x4a + (size_t)48 * 32 * 32;

    l0_kernel<<<dim3(16, 8, 48), NTHR, 0, stream>>>(
        img1, img2, x1a, x1b, x2a, x2b, x3a, x3b, x4a, x4b, acc0S, acc0C);

    tail_kernel<<<dim3(2784), NTHR, 0, stream>>>(
        x1a, x1b, x2a, x2b, x3a, x3b, x4a, x4b, accTS, accTC);

    finalize_kernel<<<1, NTHR, 0, stream>>>(acc0S, acc0C, accTS, accTC, out);
}

// Round 3
// 330.325 us; speedup vs baseline: 1.5792x; 1.5792x over previous
//
#include <hip/hip_runtime.h>

// MS-SSIM, 5 levels, 16x3x512x512 fp32, scalar fp32 out.
//
// R8: 3-launch structure (l0 -> tail -> finalize), no atomics, no memset.
// R7's multipool (recursive poolv re-reading global) caused ~600 MB of
// spill/scatter HBM traffic. R8 replaces it with a staged LDS hierarchy:
//   X1 from global (1 out/thread, v2f reads) -> LDS + global store
//   X2 from LDS-X1 -> LDS + global ; X3 from LDS-X2 ; X4 from LDS-X3
// Same 0.25f*((a+b)+(c+d)) expression at every level == repeated 2x2
// avg-pool bitwise. Per-thread state is a few floats (no spills).
// tail_kernel (levels 1..4 in one launch) and finalize are unchanged
// from R7 (verified absmax 0.0).

#define NTHR 512

typedef float v4  __attribute__((ext_vector_type(4)));
typedef float v2f __attribute__((ext_vector_type(2)));

__device__ __forceinline__ float frcp(float x) { return __builtin_amdgcn_rcpf(x); }

// One SSIM conv tile: h-pass (s/d channel reduction) -> LDS -> v-pass ->
// block reduction -> private partial slot. Identical math to R5.
template<int TROWS>
__device__ void ssim_tile(const float* __restrict__ p1, const float* __restrict__ p2,
                          int H, int tx0, int ty0,
                          v4* hb, float* red,
                          float* __restrict__ partS, float* __restrict__ partC)
{
    constexpr int HR    = TROWS + 10;          // h-rows per tile
    constexpr int OPT   = TROWS * 32 / NTHR;   // output rows per thread
    constexpr int PITCH = 33;                  // v4 units per LDS row
    constexpr int NW    = NTHR / 64;           // waves per block

    const float GW[11] = {0.00102840f, 0.00759877f, 0.03600070f, 0.10936069f,
                          0.21300636f, 0.26601172f, 0.21300636f, 0.10936069f,
                          0.03600070f, 0.00759877f, 0.00102840f};
    const float C1 = 1e-4f, C2 = 9e-4f;

    const int tid   = threadIdx.x;
    const int outHW = H - 10;

    // ---- horizontal pass: HR rows x 8 col-groups (4 cols each)
    for (int task = tid; task < HR * 8; task += NTHR) {
        const int r  = task >> 3, cg2 = task & 7;
        const int gr = ty0 + r;
        const int c0 = tx0 + cg2 * 4;
        v4 hs = 0.f, hd = 0.f, hss = 0.f, hdd = 0.f;
        if (gr < H) {
            float s[16], d[16];
            if (c0 + 16 <= H) {
                const float* pa = p1 + (size_t)gr * H + c0;
                const float* pb = p2 + (size_t)gr * H + c0;
                #pragma unroll
                for (int q = 0; q < 4; ++q) {
                    v4 va = *(const v4*)(pa + 4 * q);
                    v4 vb = *(const v4*)(pb + 4 * q);
                    v4 sv = va + vb, dv = va - vb;
                    s[4*q+0] = sv.x; s[4*q+1] = sv.y; s[4*q+2] = sv.z; s[4*q+3] = sv.w;
                    d[4*q+0] = dv.x; d[4*q+1] = dv.y; d[4*q+2] = dv.z; d[4*q+3] = dv.w;
                }
            } else {
                #pragma unroll
                for (int q = 0; q < 16; ++q) {
                    int cc = c0 + q;
                    float a = (cc < H) ? p1[(size_t)gr * H + cc] : 0.f;
                    float b = (cc < H) ? p2[(size_t)gr * H + cc] : 0.f;
                    s[q] = a + b; d[q] = a - b;
                }
            }
            #pragma unroll
            for (int j = 0; j < 11; ++j) {
                float w = GW[j];
                v4 sv = {s[j], s[j+1], s[j+2], s[j+3]};
                v4 dv = {d[j], d[j+1], d[j+2], d[j+3]};
                v4 wsv = w * sv, wdv = w * dv;
                hs += wsv; hd += wdv; hss += wsv * sv; hdd += wdv * dv;
            }
        }
        v4* row = &hb[r * PITCH + cg2 * 4];
        row[0] = (v4){hs.x, hd.x, hss.x, hdd.x};
        row[1] = (v4){hs.y, hd.y, hss.y, hdd.y};
        row[2] = (v4){hs.z, hd.z, hss.z, hdd.z};
        row[3] = (v4){hs.w, hd.w, hss.w, hdd.w};
    }
    __syncthreads();

    // ---- vertical pass + ssim/cs: thread = 1 column x OPT rows
    const int col  = tid & 31;
    const int row0 = (tid >> 5) * OPT;
    const float colm = (tx0 + col < outHW) ? 1.f : 0.f;
    v4 A[OPT];
    #pragma unroll
    for (int k = 0; k < OPT; ++k) A[k] = 0.f;

    #pragma unroll
    for (int r = 0; r < OPT + 10; ++r) {
        v4 h = hb[(row0 + r) * PITCH + col];
        #pragma unroll
        for (int k = 0; k < OPT; ++k) {
            const int j = r - k;
            if (j >= 0 && j < 11) A[k] += GW[j] * h;
        }
    }

    float ssim_t = 0.f, cs_t = 0.f;
    #pragma unroll
    for (int k = 0; k < OPT; ++k) {
        float mask = colm * ((ty0 + row0 + k < outHW) ? 1.f : 0.f);
        float mu_s = A[k].x, mu_d = A[k].y;
        float P = mu_s * mu_s, Q = mu_d * mu_d;
        float U = A[k].z - P, V = A[k].w - Q;
        float v1 = 0.5f * (U - V) + C2;
        float v2 = 0.5f * (U + V) + C2;
        float n1 = 0.5f * (P - Q) + C1;
        float d1 = 0.5f * (P + Q) + C1;
        float csv = v1 * frcp(v2);
        float ssv = n1 * csv * frcp(d1);
        cs_t   += mask * csv;
        ssim_t += mask * ssv;
    }

    // ---- block reduction -> private partial slot (no atomics)
    #pragma unroll
    for (int off = 32; off > 0; off >>= 1) {
        ssim_t += __shfl_down(ssim_t, off);
        cs_t   += __shfl_down(cs_t, off);
    }
    int wave = tid >> 6, lane = tid & 63;
    if (lane == 0) { red[wave] = ssim_t; red[NW + wave] = cs_t; }
    __syncthreads();
    if (tid == 0) {
        float s = 0.f, c = 0.f;
        #pragma unroll
        for (int w = 0; w < NW; ++w) { s += red[w]; c += red[NW + w]; }
        partS[0] = s; partC[0] = c;
    }
}

// ---- level 0: staged-LDS multipool + SSIM tile.
// Block core = 64 rows x 32 cols (grid 16x8x48 tiles 512x512 exactly).
// Pool patches per block: X1 32x16, X2 16x8, X3 8x4, X4 4x2.
__global__ __launch_bounds__(NTHR, 8) void l0_kernel(
    const float* __restrict__ img1, const float* __restrict__ img2,
    float* __restrict__ x1a, float* __restrict__ x1b,
    float* __restrict__ x2a, float* __restrict__ x2b,
    float* __restrict__ x3a, float* __restrict__ x3b,
    float* __restrict__ x4a, float* __restrict__ x4b,
    float* __restrict__ accS, float* __restrict__ accC)
{
    __shared__ v4 hb[74 * 33];
    __shared__ float red[16];

    const int tid = threadIdx.x;
    const int nc  = blockIdx.z;
    const int tx0 = blockIdx.x * 32;
    const int ty0 = blockIdx.y * 64;
    const int H   = 512;
    const float* p1 = img1 + (size_t)nc * H * H;
    const float* p2 = img2 + (size_t)nc * H * H;

    // LDS scratch (aliases hb; h-pass overwrites after the last sync):
    //   xl1a[512] xl1b[512] : X1 patches (32x16)
    //   xl2a[128] xl2b[128] : X2 patches (16x8)
    //   xl3a[32]  xl3b[32]  : X3 patches (8x4)
    float* xp   = (float*)hb;
    float* xl1a = xp;          float* xl1b = xp + 512;
    float* xl2a = xp + 1024;   float* xl2b = xp + 1152;
    float* xl3a = xp + 1280;   float* xl3b = xp + 1312;

    // -- step 1: X1 from global (1 output/thread), store LDS + global
    {
        const int r = tid >> 4, c = tid & 15;          // 32 x 16
        const int iy = ty0 + 2 * r, ix = tx0 + 2 * c;
        v2f a0 = *(const v2f*)(p1 + (size_t)iy * H + ix);
        v2f a1 = *(const v2f*)(p1 + (size_t)(iy + 1) * H + ix);
        v2f b0 = *(const v2f*)(p2 + (size_t)iy * H + ix);
        v2f b1 = *(const v2f*)(p2 + (size_t)(iy + 1) * H + ix);
        float va = 0.25f * ((a0.x + a0.y) + (a1.x + a1.y));
        float vb = 0.25f * ((b0.x + b0.y) + (b1.x + b1.y));
        xl1a[tid] = va; xl1b[tid] = vb;
        size_t o = (size_t)nc * 256 * 256 + (size_t)((ty0 >> 1) + r) * 256 + ((tx0 >> 1) + c);
        x1a[o] = va; x1b[o] = vb;
    }
    __syncthreads();

    // -- step 2: X2 from LDS-X1 (threads 0..255; 0..127 img1, 128..255 img2)
    if (tid < 256) {
        const int im = tid >> 7, t = tid & 127;
        const int r = t >> 3, c = t & 7;               // 16 x 8
        const float* src = im ? xl1b : xl1a;
        float* dstl      = im ? xl2b : xl2a;
        float* dstg      = im ? x2b  : x2a;
        const float* q0 = src + (2 * r) * 16 + 2 * c;
        const float* q1 = q0 + 16;
        float v = 0.25f * ((q0[0] + q0[1]) + (q1[0] + q1[1]));
        dstl[t] = v;
        size_t o = (size_t)nc * 128 * 128 + (size_t)((ty0 >> 2) + r) * 128 + ((tx0 >> 2) + c);
        dstg[o] = v;
    }
    __syncthreads();

    // -- step 3: X3 from LDS-X2 (threads 0..63)
    if (tid < 64) {
        const int im = tid >> 5, t = tid & 31;
        const int r = t >> 2, c = t & 3;               // 8 x 4
        const float* src = im ? xl2b : xl2a;
        float* dstl      = im ? xl3b : xl3a;
        float* dstg      = im ? x3b  : x3a;
        const float* q0 = src + (2 * r) * 8 + 2 * c;
        const float* q1 = q0 + 8;
        float v = 0.25f * ((q0[0] + q0[1]) + (q1[0] + q1[1]));
        dstl[t] = v;
        size_t o = (size_t)nc * 64 * 64 + (size_t)((ty0 >> 3) + r) * 64 + ((tx0 >> 3) + c);
        dstg[o] = v;
    }
    __syncthreads();

    // -- step 4: X4 from LDS-X3 (threads 0..15)
    if (tid < 16) {
        const int im = tid >> 3, t = tid & 7;
        const int r = t >> 1, c = t & 1;               // 4 x 2
        const float* src = im ? xl3b : xl3a;
        float* dstg      = im ? x4b  : x4a;
        const float* q0 = src + (2 * r) * 4 + 2 * c;
        const float* q1 = q0 + 4;
        float v = 0.25f * ((q0[0] + q0[1]) + (q1[0] + q1[1]));
        size_t o = (size_t)nc * 32 * 32 + (size_t)((ty0 >> 4) + r) * 32 + ((tx0 >> 4) + c);
        dstg[o] = v;
    }
    __syncthreads();   // pool scratch dead; h-pass may overwrite hb

    int fb = (int)blockIdx.x + (int)gridDim.x * ((int)blockIdx.y + (int)gridDim.y * (int)blockIdx.z);
    ssim_tile<64>(p1, p2, H, tx0, ty0, hb, red, accS + fb, accC + fb);
}

// ---- levels 1..4 in one launch; block-uniform template dispatch
//   [0,1536):   L1  H=256 T=64  ct=8 rt=4
//   [1536,2304):L2  H=128 T=32  ct=4 rt=4
//   [2304,2688):L3  H=64  T=16  ct=2 rt=4
//   [2688,2784):L4  H=32  T=16  ct=1 rt=2
__global__ __launch_bounds__(NTHR, 8) void tail_kernel(
    const float* __restrict__ x1a, const float* __restrict__ x1b,
    const float* __restrict__ x2a, const float* __restrict__ x2b,
    const float* __restrict__ x3a, const float* __restrict__ x3b,
    const float* __restrict__ x4a, const float* __restrict__ x4b,
    float* __restrict__ accTS, float* __restrict__ accTC)
{
    __shared__ v4 hb[74 * 33];
    __shared__ float red[16];

    const int b = (int)blockIdx.x;
    if (b < 1536) {
        const int H = 256, ct = 8, rt = 4;
        int cx = b % ct, rem = b / ct, cy = rem % rt, nc = rem / rt;
        const float* p1 = x1a + (size_t)nc * H * H;
        const float* p2 = x1b + (size_t)nc * H * H;
        ssim_tile<64>(p1, p2, H, cx * 32, cy * 64, hb, red, accTS + b, accTC + b);
    } else if (b < 2304) {
        const int H = 128, ct = 4, rt = 4;
        int lb = b - 1536;
        int cx = lb % ct, rem = lb / ct, cy = rem % rt, nc = rem / rt;
        const float* p1 = x2a + (size_t)nc * H * H;
        const float* p2 = x2b + (size_t)nc * H * H;
        ssim_tile<32>(p1, p2, H, cx * 32, cy * 32, hb, red, accTS + b, accTC + b);
    } else if (b < 2688) {
        const int H = 64, ct = 2, rt = 4;
        int lb = b - 2304;
        int cx = lb % ct, rem = lb / ct, cy = rem % rt, nc = rem / rt;
        const float* p1 = x3a + (size_t)nc * H * H;
        const float* p2 = x3b + (size_t)nc * H * H;
        ssim_tile<16>(p1, p2, H, cx * 32, cy * 16, hb, red, accTS + b, accTC + b);
    } else {
        const int H = 32, ct = 1, rt = 2;
        int lb = b - 2688;
        int cx = lb % ct, rem = lb / ct, cy = rem % rt, nc = rem / rt;
        const float* p1 = x4a + (size_t)nc * H * H;
        const float* p2 = x4b + (size_t)nc * H * H;
        ssim_tile<16>(p1, p2, H, cx * 32, cy * 16, hb, red, accTS + b, accTC + b);
    }
}

// ---- finalize: sum partial slots, pow weights
__global__ void finalize_kernel(const float* __restrict__ acc0S, const float* __restrict__ acc0C,
                                const float* __restrict__ accTS, const float* __restrict__ accTC,
                                float* __restrict__ out)
{
    __shared__ float sm[10];
    __shared__ float wred[8];
    const int tid  = (int)threadIdx.x;
    const int wave = tid >> 6, lane = tid & 63;
    const int st[5] = {0, 0, 1536, 2304, 2688};
    const int en[5] = {6144, 1536, 2304, 2688, 2784};

    for (int srs = 0; srs < 10; ++srs) {
        int l = srs >> 1;
        const float* base = (srs & 1) ? (l == 0 ? acc0C : accTC)
                                      : (l == 0 ? acc0S : accTS);
        float p = 0.f;
        for (int i = st[l] + tid; i < en[l]; i += NTHR) p += base[i];
        #pragma unroll
        for (int o = 32; o > 0; o >>= 1) p += __shfl_down(p, o);
        if (lane == 0) wred[wave] = p;
        __syncthreads();
        if (tid == 0) {
            float t = 0.f;
            #pragma unroll
            for (int w = 0; w < 8; ++w) t += wred[w];
            sm[srs] = t;
        }
        __syncthreads();
    }

    if (tid == 0) {
        const float w[5] = {0.0448f, 0.2856f, 0.3001f, 0.2363f, 0.1333f};
        float ms[5], mc[5];
        for (int l = 0; l < 5; ++l) {
            int oh = (512 >> l) - 10;
            float cnt = 48.f * (float)oh * (float)oh;
            ms[l] = (sm[2 * l] / cnt + 1.f) * 0.5f;
            mc[l] = (sm[2 * l + 1] / cnt + 1.f) * 0.5f;
        }
        float p2 = powf(ms[4], w[4]);
        float r = 1.f;
        for (int i = 0; i < 4; ++i) r *= powf(mc[i], w[i]) * p2;
        out[0] = r;
    }
}

extern "C" void kernel_launch(void* const* d_in, const int* in_sizes, int n_in,
                              void* d_out, int out_size, void* d_ws, size_t ws_size,
                              hipStream_t stream)
{
    (void)in_sizes; (void)n_in; (void)out_size; (void)ws_size;
    const float* img1 = (const float*)d_in[0];
    const float* img2 = (const float*)d_in[1];
    float* out = (float*)d_out;
    float* ws  = (float*)d_ws;

    // workspace layout (floats):
    //   acc0S[6144] acc0C[6144] accTS[2784] accTC[2784]  (per-block partials)
    //   X1a X1b X2a X2b X3a X3b X4a X4b                  (pyramid buffers)
    float* acc0S = ws;
    float* acc0C = acc0S + 6144;
    float* accTS = acc0C + 6144;
    float* accTC = accTS + 2784;
    float* bufs  = accTC + 2784;
    float* x1a = bufs;
    float* x1b = x1a + (size_t)48 * 256 * 256;
    float* x2a = x1b + (size_t)48 * 256 * 256;
    float* x2b = x2a + (size_t)48 * 128 * 128;
    float* x3a = x2b + (size_t)48 * 128 * 128;
    float* x3b = x3a + (size_t)48 * 64 * 64;
    float* x4a = x3b + (size_t)48 * 64 * 64;
    float* x4b = x4a + (size_t)48 * 32 * 32;

    l0_kernel<<<dim3(16, 8, 48), NTHR, 0, stream>>>(
        img1, img2, x1a, x1b, x2a, x2b, x3a, x3b, x4a, x4b, acc0S, acc0C);

    tail_kernel<<<dim3(2784), NTHR, 0, stream>>>(
        x1a, x1b, x2a, x2b, x3a, x3b, x4a, x4b, accTS, accTC);

    finalize_kernel<<<1, NTHR, 0, stream>>>(acc0S, acc0C, accTS, accTC, out);
}

// Round 4
// 225.850 us; speedup vs baseline: 2.3098x; 1.4626x over previous
//
#include <hip/hip_runtime.h>

// MS-SSIM, 5 levels, 16x3x512x512 fp32, scalar fp32 out.
//
// R9: 3 launches (l0 -> tail -> finalize); ONLY X1 is ever materialized.
// R8 post-mortem: writing X2..X4 from 6144 blocks = 8/4/2-float row strips
// per block -> every 128B line RMW'd by 4-16 blocks across XCDs -> +530 MB
// HBM traffic. Fix: deep levels are recomputed where consumed.
//  - l0_kernel: R5's proven tile (ssim0) + X1 store (proven pattern).
//  - tail_kernel (2784 blocks, one launch):
//      L1 (1536): direct tile on X1 (proven code path).
//      L2 (768):  h-pass inline-pools 2x2 from X1 (global, L3-hot reads).
//      L3 (384):  stage X2-region (52x88) in LDS from X1 (exact pool tree),
//                 h-pass pools 2x2 from LDS.
//      L4 (96):   stage X3-region (52x88) in LDS from X1 (pool^2 tree),
//                 h-pass pools 2x2 from LDS.
//    All pooling uses the exact 0.25f*((a+b)+(c+d)) grouping at every
//    step == reference repeated avg_pool2, bitwise.
//  - finalize: sums per-block partial slots (written unconditionally ->
//    re-poison safe), applies pow weights.

#define NTHR 512

typedef float v4  __attribute__((ext_vector_type(4)));
typedef float v2f __attribute__((ext_vector_type(2)));

__device__ __forceinline__ float frcp(float x) { return __builtin_amdgcn_rcpf(x); }

#define GW_DEF const float GW[11] = {0.00102840f, 0.00759877f, 0.03600070f, \
    0.10936069f, 0.21300636f, 0.26601172f, 0.21300636f, 0.10936069f,        \
    0.03600070f, 0.00759877f, 0.00102840f};

// 11-tap conv of s[]/d[] into the 4 h-channels. Exact R5 statement order.
__device__ __forceinline__ void conv11(const float* s, const float* d,
                                       v4& hs, v4& hd, v4& hss, v4& hdd)
{
    GW_DEF
    #pragma unroll
    for (int j = 0; j < 11; ++j) {
        float w = GW[j];
        v4 sv = {s[j], s[j+1], s[j+2], s[j+3]};
        v4 dv = {d[j], d[j+1], d[j+2], d[j+3]};
        v4 wsv = w * sv, wdv = w * dv;
        hs += wsv; hd += wdv; hss += wsv * sv; hdd += wdv * dv;
    }
}

// ---- h-pass variant 1: direct source (level pixels in global). R5 code.
template<int TROWS>
__device__ void hpass_direct(const float* __restrict__ p1, const float* __restrict__ p2,
                             int H, int tx0, int ty0, v4* hb)
{
    constexpr int HR = TROWS + 10;
    for (int task = threadIdx.x; task < HR * 8; task += NTHR) {
        const int r = task >> 3, cg2 = task & 7;
        const int gr = ty0 + r;
        const int c0 = tx0 + cg2 * 4;
        v4 hs = 0.f, hd = 0.f, hss = 0.f, hdd = 0.f;
        if (gr < H) {
            float s[16], d[16];
            if (c0 + 16 <= H) {
                const float* pa = p1 + (size_t)gr * H + c0;
                const float* pb = p2 + (size_t)gr * H + c0;
                #pragma unroll
                for (int q = 0; q < 4; ++q) {
                    v4 va = *(const v4*)(pa + 4 * q);
                    v4 vb = *(const v4*)(pb + 4 * q);
                    v4 sv = va + vb, dv = va - vb;
                    s[4*q+0] = sv.x; s[4*q+1] = sv.y; s[4*q+2] = sv.z; s[4*q+3] = sv.w;
                    d[4*q+0] = dv.x; d[4*q+1] = dv.y; d[4*q+2] = dv.z; d[4*q+3] = dv.w;
                }
            } else {
                #pragma unroll
                for (int q = 0; q < 16; ++q) {
                    int cc = c0 + q;
                    float a = (cc < H) ? p1[(size_t)gr * H + cc] : 0.f;
                    float b = (cc < H) ? p2[(size_t)gr * H + cc] : 0.f;
                    s[q] = a + b; d[q] = a - b;
                }
            }
            conv11(s, d, hs, hd, hss, hdd);
        }
        v4* row = &hb[r * 33 + cg2 * 4];
        row[0] = (v4){hs.x, hd.x, hss.x, hdd.x};
        row[1] = (v4){hs.y, hd.y, hss.y, hdd.y};
        row[2] = (v4){hs.z, hd.z, hss.z, hdd.z};
        row[3] = (v4){hs.w, hd.w, hss.w, hdd.w};
    }
}

// ---- h-pass variant 2: level pixels = 2x2 pool of X1 (global), computed
// inline. H = level dim; source dim = 2H.
template<int TROWS>
__device__ void hpass_pool1(const float* __restrict__ q1, const float* __restrict__ q2,
                            int H, int tx0, int ty0, v4* hb)
{
    constexpr int HR = TROWS + 10;
    const int HS = 2 * H;
    for (int task = threadIdx.x; task < HR * 8; task += NTHR) {
        const int r = task >> 3, cg2 = task & 7;
        const int gr = ty0 + r;
        const int c0 = tx0 + cg2 * 4;
        v4 hs = 0.f, hd = 0.f, hss = 0.f, hdd = 0.f;
        if (gr < H) {
            float s[16], d[16];
            const int iy = 2 * gr;
            if (c0 + 16 <= H) {
                const float* a0 = q1 + (size_t)iy * HS + 2 * c0;
                const float* b0 = q2 + (size_t)iy * HS + 2 * c0;
                #pragma unroll
                for (int q = 0; q < 8; ++q) {        // 2 outputs per v4 pair
                    v4 xa0 = *(const v4*)(a0 + 4 * q);
                    v4 xa1 = *(const v4*)(a0 + HS + 4 * q);
                    v4 xb0 = *(const v4*)(b0 + 4 * q);
                    v4 xb1 = *(const v4*)(b0 + HS + 4 * q);
                    float pa0 = 0.25f * ((xa0.x + xa0.y) + (xa1.x + xa1.y));
                    float pa1 = 0.25f * ((xa0.z + xa0.w) + (xa1.z + xa1.w));
                    float pb0 = 0.25f * ((xb0.x + xb0.y) + (xb1.x + xb1.y));
                    float pb1 = 0.25f * ((xb0.z + xb0.w) + (xb1.z + xb1.w));
                    s[2*q]   = pa0 + pb0; d[2*q]   = pa0 - pb0;
                    s[2*q+1] = pa1 + pb1; d[2*q+1] = pa1 - pb1;
                }
            } else {
                #pragma unroll
                for (int q = 0; q < 16; ++q) {
                    int cc = c0 + q;
                    float pa = 0.f, pb = 0.f;
                    if (cc < H) {
                        const float* qa = q1 + (size_t)iy * HS + 2 * cc;
                        const float* qb = q2 + (size_t)iy * HS + 2 * cc;
                        pa = 0.25f * ((qa[0] + qa[1]) + (qa[HS] + qa[HS + 1]));
                        pb = 0.25f * ((qb[0] + qb[1]) + (qb[HS] + qb[HS + 1]));
                    }
                    s[q] = pa + pb; d[q] = pa - pb;
                }
            }
            conv11(s, d, hs, hd, hss, hdd);
        }
        v4* row = &hb[r * 33 + cg2 * 4];
        row[0] = (v4){hs.x, hd.x, hss.x, hdd.x};
        row[1] = (v4){hs.y, hd.y, hss.y, hdd.y};
        row[2] = (v4){hs.z, hd.z, hss.z, hdd.z};
        row[3] = (v4){hs.w, hd.w, hss.w, hdd.w};
    }
}

// ---- h-pass variant 3: level pixels = 2x2 pool of an LDS-staged region
// (pitch 89, origin = source coords (2*ty0, 2*tx0)). H = level dim.
template<int TROWS>
__device__ void hpass_lds(const float* la, const float* lb,
                          int H, int tx0, int ty0, v4* hb)
{
    constexpr int HR = TROWS + 10;
    for (int task = threadIdx.x; task < HR * 8; task += NTHR) {
        const int r = task >> 3, cg2 = task & 7;
        const int gr = ty0 + r;
        const int c0 = tx0 + cg2 * 4;
        v4 hs = 0.f, hd = 0.f, hss = 0.f, hdd = 0.f;
        if (gr < H) {
            float s[16], d[16];
            const int lr = 2 * r;
            #pragma unroll
            for (int q = 0; q < 16; ++q) {
                int cc = c0 + q;
                float pa = 0.f, pb = 0.f;
                if (cc < H) {
                    int lc = 2 * (cc - tx0);
                    const float* a0 = la + lr * 89 + lc;
                    const float* b0 = lb + lr * 89 + lc;
                    pa = 0.25f * ((a0[0] + a0[1]) + (a0[89] + a0[90]));
                    pb = 0.25f * ((b0[0] + b0[1]) + (b0[89] + b0[90]));
                }
                s[q] = pa + pb; d[q] = pa - pb;
            }
            conv11(s, d, hs, hd, hss, hdd);
        }
        v4* row = &hb[r * 33 + cg2 * 4];
        row[0] = (v4){hs.x, hd.x, hss.x, hdd.x};
        row[1] = (v4){hs.y, hd.y, hss.y, hdd.y};
        row[2] = (v4){hs.z, hd.z, hss.z, hdd.z};
        row[3] = (v4){hs.w, hd.w, hss.w, hdd.w};
    }
}

// Stage a 52x88 region of pool1(X1) (= X2-level values) into LDS.
// DL = dest level dim (128); source dim 2*DL; region origin (2*ty0, 2*tx0).
__device__ void stage_pool1(const float* __restrict__ s1, const float* __restrict__ s2,
                            int DL, int tx0, int ty0, float* la, float* lb)
{
    const int SD = 2 * DL;
    for (int t = threadIdx.x; t < 2 * 52 * 44; t += NTHR) {
        int im = t >= 52 * 44; int tt = im ? t - 52 * 44 : t;
        int rr = tt / 44, cp = tt % 44;
        int xr = 2 * ty0 + rr, xc = 2 * tx0 + 2 * cp;
        const float* sp = im ? s2 : s1;
        float* lp = im ? lb : la;
        float v0 = 0.f, v1 = 0.f;
        if (xr < DL && xc < DL) {
            const float* q0 = sp + (size_t)(2 * xr) * SD + 2 * xc;
            v4 r0 = *(const v4*)q0;
            v4 r1 = *(const v4*)(q0 + SD);
            v0 = 0.25f * ((r0.x + r0.y) + (r1.x + r1.y));
            v1 = 0.25f * ((r0.z + r0.w) + (r1.z + r1.w));
        }
        lp[rr * 89 + 2 * cp]     = v0;
        lp[rr * 89 + 2 * cp + 1] = v1;
    }
}

// Stage a 52x88 region of pool2(X1) (= X3-level values) into LDS.
// DL = dest level dim (64); source dim 4*DL; region origin (2*ty0, 0).
__device__ void stage_pool2(const float* __restrict__ s1, const float* __restrict__ s2,
                            int DL, int ty0, float* la, float* lb)
{
    const int SD = 4 * DL;
    for (int t = threadIdx.x; t < 2 * 52 * 88; t += NTHR) {
        int im = t >= 52 * 88; int tt = im ? t - 52 * 88 : t;
        int rr = tt / 88, cc = tt % 88;
        int yr = 2 * ty0 + rr, yc = cc;
        const float* sp = im ? s2 : s1;
        float* lp = im ? lb : la;
        float v = 0.f;
        if (yr < DL && yc < DL) {
            const float* q = sp + (size_t)(4 * yr) * SD + 4 * yc;
            v4 r0 = *(const v4*)q;
            v4 r1 = *(const v4*)(q + SD);
            v4 r2 = *(const v4*)(q + 2 * SD);
            v4 r3 = *(const v4*)(q + 3 * SD);
            float a00 = 0.25f * ((r0.x + r0.y) + (r1.x + r1.y));
            float a01 = 0.25f * ((r0.z + r0.w) + (r1.z + r1.w));
            float a10 = 0.25f * ((r2.x + r2.y) + (r3.x + r3.y));
            float a11 = 0.25f * ((r2.z + r2.w) + (r3.z + r3.w));
            v = 0.25f * ((a00 + a01) + (a10 + a11));
        }
        lp[rr * 89 + cc] = v;
    }
}

// ---- vertical pass + ssim/cs + block reduction (R5 code, verbatim)
template<int TROWS>
__device__ void vpass_reduce(int H, int tx0, int ty0, const v4* hb, float* red,
                             float* __restrict__ partS, float* __restrict__ partC)
{
    constexpr int OPT = TROWS * 32 / NTHR;
    constexpr int NW  = NTHR / 64;
    GW_DEF
    const float C1 = 1e-4f, C2 = 9e-4f;
    const int tid   = threadIdx.x;
    const int outHW = H - 10;
    const int col   = tid & 31;
    const int row0  = (tid >> 5) * OPT;
    const float colm = (tx0 + col < outHW) ? 1.f : 0.f;
    v4 A[OPT];
    #pragma unroll
    for (int k = 0; k < OPT; ++k) A[k] = 0.f;

    #pragma unroll
    for (int r = 0; r < OPT + 10; ++r) {
        v4 h = hb[(row0 + r) * 33 + col];
        #pragma unroll
        for (int k = 0; k < OPT; ++k) {
            const int j = r - k;
            if (j >= 0 && j < 11) A[k] += GW[j] * h;
        }
    }

    float ssim_t = 0.f, cs_t = 0.f;
    #pragma unroll
    for (int k = 0; k < OPT; ++k) {
        float mask = colm * ((ty0 + row0 + k < outHW) ? 1.f : 0.f);
        float mu_s = A[k].x, mu_d = A[k].y;
        float P = mu_s * mu_s, Q = mu_d * mu_d;
        float U = A[k].z - P, V = A[k].w - Q;
        float v1 = 0.5f * (U - V) + C2;
        float v2 = 0.5f * (U + V) + C2;
        float n1 = 0.5f * (P - Q) + C1;
        float d1 = 0.5f * (P + Q) + C1;
        float csv = v1 * frcp(v2);
        float ssv = n1 * csv * frcp(d1);
        cs_t   += mask * csv;
        ssim_t += mask * ssv;
    }

    #pragma unroll
    for (int off = 32; off > 0; off >>= 1) {
        ssim_t += __shfl_down(ssim_t, off);
        cs_t   += __shfl_down(cs_t, off);
    }
    int wave = tid >> 6, lane = tid & 63;
    if (lane == 0) { red[wave] = ssim_t; red[NW + wave] = cs_t; }
    __syncthreads();
    if (tid == 0) {
        float s = 0.f, c = 0.f;
        #pragma unroll
        for (int w = 0; w < NW; ++w) { s += red[w]; c += red[NW + w]; }
        partS[0] = s; partC[0] = c;
    }
}

// ---- level 0: ssim0 + X1 store (R5-proven structure)
__global__ __launch_bounds__(NTHR, 8) void l0_kernel(
    const float* __restrict__ img1, const float* __restrict__ img2,
    float* __restrict__ x1a, float* __restrict__ x1b,
    float* __restrict__ accS, float* __restrict__ accC)
{
    __shared__ v4 hb[74 * 33];
    __shared__ float red[16];

    const int tid = threadIdx.x;
    const int nc  = blockIdx.z;
    const int tx0 = blockIdx.x * 32;
    const int ty0 = blockIdx.y * 64;
    const int H   = 512;
    const float* p1 = img1 + (size_t)nc * H * H;
    const float* p2 = img2 + (size_t)nc * H * H;

    // X1 for the block's 64x32 core (grid tiles 512x512 exactly)
    {
        const int r = tid >> 4, c = tid & 15;          // 32 x 16
        const int iy = ty0 + 2 * r, ix = tx0 + 2 * c;
        v2f a0 = *(const v2f*)(p1 + (size_t)iy * H + ix);
        v2f a1 = *(const v2f*)(p1 + (size_t)(iy + 1) * H + ix);
        v2f b0 = *(const v2f*)(p2 + (size_t)iy * H + ix);
        v2f b1 = *(const v2f*)(p2 + (size_t)(iy + 1) * H + ix);
        size_t o = (size_t)nc * 256 * 256 + (size_t)((ty0 >> 1) + r) * 256 + ((tx0 >> 1) + c);
        x1a[o] = 0.25f * ((a0.x + a0.y) + (a1.x + a1.y));
        x1b[o] = 0.25f * ((b0.x + b0.y) + (b1.x + b1.y));
    }

    hpass_direct<64>(p1, p2, H, tx0, ty0, hb);
    __syncthreads();
    int fb = (int)blockIdx.x + 16 * ((int)blockIdx.y + 8 * nc);
    vpass_reduce<64>(H, tx0, ty0, hb, red, accS + fb, accC + fb);
}

// ---- levels 1..4, one launch, deep levels recomputed from X1
//   [0,1536):    L1 H=256 T=64 ct=8 rt=4   direct on X1
//   [1536,2304): L2 H=128 T=32 ct=4 rt=4   inline pool1 of X1
//   [2304,2688): L3 H=64  T=16 ct=2 rt=4   LDS-staged pool1 region
//   [2688,2784): L4 H=32  T=16 ct=1 rt=2   LDS-staged pool2 region
__global__ __launch_bounds__(NTHR, 6) void tail_kernel(
    const float* __restrict__ x1a, const float* __restrict__ x1b,
    float* __restrict__ accTS, float* __restrict__ accTC)
{
    __shared__ v4 smemv[3172];          // 12688 floats = 50,752 B union
    __shared__ float red[16];
    v4* hb    = smemv;                  // T64 path: 9768 floats
    float* la = (float*)smemv + 3432;   // T16 paths: hb=3432 floats, then
    float* lb = la + 52 * 89;           // two 52x89 regions = 9256 floats

    const int b = (int)blockIdx.x;
    if (b < 1536) {
        const int H = 256;
        int cx = b & 7, rem = b >> 3, cy = rem & 3, nc = rem >> 2;
        const float* p1 = x1a + (size_t)nc * H * H;
        const float* p2 = x1b + (size_t)nc * H * H;
        int tx0 = cx * 32, ty0 = cy * 64;
        hpass_direct<64>(p1, p2, H, tx0, ty0, hb);
        __syncthreads();
        vpass_reduce<64>(H, tx0, ty0, hb, red, accTS + b, accTC + b);
    } else if (b < 2304) {
        const int H = 128;
        int lbk = b - 1536;
        int cx = lbk & 3, rem = lbk >> 2, cy = rem & 3, nc = rem >> 2;
        const float* q1 = x1a + (size_t)nc * 256 * 256;
        const float* q2 = x1b + (size_t)nc * 256 * 256;
        int tx0 = cx * 32, ty0 = cy * 32;
        hpass_pool1<32>(q1, q2, H, tx0, ty0, hb);
        __syncthreads();
        vpass_reduce<32>(H, tx0, ty0, hb, red, accTS + b, accTC + b);
    } else if (b < 2688) {
        const int H = 64;
        int lbk = b - 2304;
        int cx = lbk & 1, rem = lbk >> 1, cy = rem & 3, nc = rem >> 2;
        const float* q1 = x1a + (size_t)nc * 256 * 256;
        const float* q2 = x1b + (size_t)nc * 256 * 256;
        int tx0 = cx * 32, ty0 = cy * 16;
        stage_pool1(q1, q2, 128, tx0, ty0, la, lb);   // X2-level region
        __syncthreads();
        hpass_lds<16>(la, lb, H, tx0, ty0, hb);
        __syncthreads();
        vpass_reduce<16>(H, tx0, ty0, hb, red, accTS + b, accTC + b);
    } else {
        const int H = 32;
        int lbk = b - 2688;
        int cy = lbk & 1, nc = lbk >> 1;
        const float* q1 = x1a + (size_t)nc * 256 * 256;
        const float* q2 = x1b + (size_t)nc * 256 * 256;
        int tx0 = 0, ty0 = cy * 16;
        stage_pool2(q1, q2, 64, ty0, la, lb);         // X3-level region
        __syncthreads();
        hpass_lds<16>(la, lb, H, tx0, ty0, hb);
        __syncthreads();
        vpass_reduce<16>(H, tx0, ty0, hb, red, accTS + b, accTC + b);
    }
}

// ---- finalize: sum partial slots, pow weights
__global__ void finalize_kernel(const float* __restrict__ acc0S, const float* __restrict__ acc0C,
                                const float* __restrict__ accTS, const float* __restrict__ accTC,
                                float* __restrict__ out)
{
    __shared__ float sm[10];
    __shared__ float wred[8];
    const int tid  = (int)threadIdx.x;
    const int wave = tid >> 6, lane = tid & 63;
    const int st[5] = {0, 0, 1536, 2304, 2688};
    const int en[5] = {6144, 1536, 2304, 2688, 2784};

    for (int srs = 0; srs < 10; ++srs) {
        int l = srs >> 1;
        const float* base = (srs & 1) ? (l == 0 ? acc0C : accTC)
                                      : (l == 0 ? acc0S : accTS);
        float p = 0.f;
        for (int i = st[l] + tid; i < en[l]; i += NTHR) p += base[i];
        #pragma unroll
        for (int o = 32; o > 0; o >>= 1) p += __shfl_down(p, o);
        if (lane == 0) wred[wave] = p;
        __syncthreads();
        if (tid == 0) {
            float t = 0.f;
            #pragma unroll
            for (int w = 0; w < 8; ++w) t += wred[w];
            sm[srs] = t;
        }
        __syncthreads();
    }

    if (tid == 0) {
        const float w[5] = {0.0448f, 0.2856f, 0.3001f, 0.2363f, 0.1333f};
        float ms[5], mc[5];
        for (int l = 0; l < 5; ++l) {
            int oh = (512 >> l) - 10;
            float cnt = 48.f * (float)oh * (float)oh;
            ms[l] = (sm[2 * l] / cnt + 1.f) * 0.5f;
            mc[l] = (sm[2 * l + 1] / cnt + 1.f) * 0.5f;
        }
        float p2 = powf(ms[4], w[4]);
        float r = 1.f;
        for (int i = 0; i < 4; ++i) r *= powf(mc[i], w[i]) * p2;
        out[0] = r;
    }
}

extern "C" void kernel_launch(void* const* d_in, const int* in_sizes, int n_in,
                              void* d_out, int out_size, void* d_ws, size_t ws_size,
                              hipStream_t stream)
{
    (void)in_sizes; (void)n_in; (void)out_size; (void)ws_size;
    const float* img1 = (const float*)d_in[0];
    const float* img2 = (const float*)d_in[1];
    float* out = (float*)d_out;
    float* ws  = (float*)d_ws;

    // workspace (floats): acc0S[6144] acc0C[6144] accTS[2784] accTC[2784]
    //                     X1a[48*256*256] X1b[48*256*256]
    float* acc0S = ws;
    float* acc0C = acc0S + 6144;
    float* accTS = acc0C + 6144;
    float* accTC = accTS + 2784;
    float* x1a   = accTC + 2784;
    float* x1b   = x1a + (size_t)48 * 256 * 256;

    l0_kernel<<<dim3(16, 8, 48), NTHR, 0, stream>>>(img1, img2, x1a, x1b, acc0S, acc0C);
    tail_kernel<<<dim3(2784), NTHR, 0, stream>>>(x1a, x1b, accTS, accTC);
    finalize_kernel<<<1, NTHR, 0, stream>>>(acc0S, acc0C, accTS, accTC, out);
}